// Round 14
// baseline (66.230 us; speedup 1.0000x reference)
//
#include <hip/hip_runtime.h>

#define IMG_H 1080
#define IMG_W 1920
#define CH 3

typedef float f32x2 __attribute__((ext_vector_type(2)));

#if __has_builtin(__builtin_elementwise_fma)
#define FMA2(a, b, c) __builtin_elementwise_fma((a), (b), (c))
#else
#define FMA2(a, b, c) ((a) * (b) + (c))
#endif

__global__ __launch_bounds__(256)
void dssim_l1_kernel(const float* __restrict__ pred,
                     const float* __restrict__ gt,
                     float* __restrict__ out) {
    constexpr float K1 = 81.0f * 0.0001f;        // 81*C1
    constexpr float K2 = 81.0f * 0.0009f;        // 81*C2

    const f32x2 k1_ = K1, k2_ = K2;
    const f32x2 two_ = 2.0f, m2_ = -2.0f, e18_ = 18.0f, n9_ = 9.0f;
    const f32x2 mh_ = -0.5f, h_ = 0.5f, zero_ = 0.0f, one_ = 1.0f;
    const f32x2 a3_ = 0.85f / 3.0f, b3_ = 0.15f / 3.0f;

    const int lane = threadIdx.x;                               // 0..63
    const int r0   = (blockIdx.y * 4 + threadIdx.y) * 2;        // even output row
    const int b    = blockIdx.z;
    const int c0   = blockIdx.x * 128 + 2 * lane;   // loads cover cols c0..c0+3
                                                    // outputs at cols c0+1, c0+2

    // input rows r0-1 .. r0+2 with reflection
    const int rws[4] = { (r0 == 0) ? 1 : r0 - 1,
                         r0, r0 + 1,
                         (r0 + 2 == IMG_H) ? IMG_H - 2 : r0 + 2 };

    const bool ledge = (c0 == 0) && (blockIdx.x == 0);       // owns extra col 0
    const bool redge = (c0 == IMG_W - 2);                    // second output invalid

    const size_t img = (size_t)IMG_H * IMG_W;
    const float* __restrict__ pb[2 * CH] = {
        pred + (size_t)b * CH * img,
        pred + (size_t)b * CH * img + img,
        pred + (size_t)b * CH * img + 2 * img,
        gt   + (size_t)b * CH * img,
        gt   + (size_t)b * CH * img + img,
        gt   + (size_t)b * CH * img + 2 * img };

    // 32-bit dword offsets; R = M + 2 cols, except last thread where R = M
    // (then T2.x == M.x == x[1918] == reflect(1920): right edge comes out
    //  CORRECT for the col-1919 output automatically).
    const unsigned rdel = redge ? 0u : 2u;
    unsigned offM[4], offR[4];
#pragma unroll
    for (int i = 0; i < 4; ++i) {
        offM[i] = (unsigned)rws[i] * IMG_W + (unsigned)c0;
        offR[i] = offM[i] + rdel;
    }

    // ---- all 48 packed-pair loads upfront (first-consumed rows first) ----
    f32x2 mx[4][CH], rx[4][CH], my[4][CH], ry[4][CH];
#pragma unroll
    for (int i = 0; i < 4; ++i) {
#pragma unroll
        for (int c = 0; c < CH; ++c) {
            mx[i][c] = *reinterpret_cast<const f32x2*>(pb[c]      + offM[i]);
            rx[i][c] = *reinterpret_cast<const f32x2*>(pb[c]      + offR[i]);
            my[i][c] = *reinterpret_cast<const f32x2*>(pb[CH + c] + offM[i]);
            ry[i][c] = *reinterpret_cast<const f32x2*>(pb[CH + c] + offR[i]);
        }
    }

    // window accumulators, packed over the 2 output columns
    f32x2 Ax[CH], Ay[CH], Aw[CH], Ap[CH];   // rows -1,0,1 -> out row r0
    f32x2 Bx[CH], By[CH], Bw[CH], Bp[CH];   // rows 0,1,2  -> out row r0+1

#define CONSUME(I, DOA, FIRSTA, DOB, FIRSTB)                                \
    _Pragma("unroll")                                                       \
    for (int c = 0; c < CH; ++c) {                                          \
        const f32x2 T0x = mx[I][c], T2x = rx[I][c];                         \
        const f32x2 T0y = my[I][c], T2y = ry[I][c];                         \
        const f32x2 T1x = { T0x.y, T2x.x };                                 \
        const f32x2 T1y = { T0y.y, T2y.x };                                 \
        const f32x2 WX = T0x + T1x + T2x;                                   \
        const f32x2 WY = T0y + T1y + T2y;                                   \
        const f32x2 WP = FMA2(T2x, T2y, FMA2(T1x, T1y, T0x * T0y));         \
        const f32x2 WW = FMA2(T2x, T2x, FMA2(T2y, T2y, FMA2(T1x, T1x,       \
                         FMA2(T1y, T1y, FMA2(T0x, T0x, T0y * T0y)))));      \
        if (DOA) {                                                          \
            if (FIRSTA) { Ax[c] = WX; Ay[c] = WY; Aw[c] = WW; Ap[c] = WP; } \
            else        { Ax[c] += WX; Ay[c] += WY;                         \
                          Aw[c] += WW; Ap[c] += WP; }                       \
        }                                                                   \
        if (DOB) {                                                          \
            if (FIRSTB) { Bx[c] = WX; By[c] = WY; Bw[c] = WW; Bp[c] = WP; } \
            else        { Bx[c] += WX; By[c] += WY;                         \
                          Bw[c] += WW; Bp[c] += WP; }                       \
        }                                                                   \
    }

    CONSUME(0, true, true,  false, false)   // row r0-1 -> A
    CONSUME(1, true, false, true,  true)    // row r0   -> A, B

    // L1 at output cols (= T1 of the center rows)
    f32x2 l1r0 = zero_, l1r1 = zero_;
#pragma unroll
    for (int c = 0; c < CH; ++c) {
        const f32x2 tx = { mx[1][c].y, rx[1][c].x };
        const f32x2 ty = { my[1][c].y, ry[1][c].x };
#if __has_builtin(__builtin_elementwise_abs)
        l1r0 += __builtin_elementwise_abs(tx - ty);
#else
        f32x2 d = tx - ty; d.x = fabsf(d.x); d.y = fabsf(d.y); l1r0 += d;
#endif
    }

    CONSUME(2, true, false, true,  false)   // row r0+1 -> A, B
#pragma unroll
    for (int c = 0; c < CH; ++c) {
        const f32x2 tx = { mx[2][c].y, rx[2][c].x };
        const f32x2 ty = { my[2][c].y, ry[2][c].x };
#if __has_builtin(__builtin_elementwise_abs)
        l1r1 += __builtin_elementwise_abs(tx - ty);
#else
        f32x2 d = tx - ty; d.x = fabsf(d.x); d.y = fabsf(d.y); l1r1 += d;
#endif
    }

    CONSUME(3, false, false, true, false)   // row r0+2 -> B
#undef CONSUME

    // ---- packed SSIM epilogue (moments scaled by 81; cancels in n/d) ----
#define SSIM2(AX, AY, AW, AP, ACC)                                          \
    {                                                                       \
        const f32x2 u  = (AX) * (AY);                                       \
        const f32x2 v  = FMA2((AY), (AY), (AX) * (AX));                     \
        const f32x2 n1 = FMA2(two_, u, k1_);                                \
        const f32x2 n2 = FMA2(e18_, (AP), FMA2(m2_, u, k2_));               \
        const f32x2 d1 = v + k1_;                                           \
        const f32x2 d2 = FMA2(n9_, (AW), k2_) - v;                          \
        const f32x2 nd = n1 * n2, dd = d1 * d2;                             \
        f32x2 rc;                                                           \
        rc.x = __builtin_amdgcn_rcpf(dd.x);                                 \
        rc.y = __builtin_amdgcn_rcpf(dd.y);                                 \
        f32x2 s = FMA2(mh_, nd * rc, h_);                                   \
        s = __builtin_elementwise_min(                                      \
                __builtin_elementwise_max(s, zero_), one_);                 \
        ACC = FMA2(a3_, s, ACC);                                            \
    }

    f32x2 o0 = b3_ * l1r0;
    f32x2 o1 = b3_ * l1r1;
#pragma unroll
    for (int c = 0; c < CH; ++c) {
        SSIM2(Ax[c], Ay[c], Aw[c], Ap[c], o0)
        SSIM2(Bx[c], By[c], Bw[c], Bp[c], o1)
    }
#undef SSIM2

    float* op0 = out + ((size_t)b * IMG_H + r0) * IMG_W;
    float* op1 = op0 + IMG_W;
    op0[c0 + 1] = o0.x;
    op1[c0 + 1] = o1.x;
    if (!redge) {
        op0[c0 + 2] = o0.y;
        op1[c0 + 2] = o1.y;
    }

    // ---- image-left column 0 (window cols {1,0,1}): one lane per 540 waves ----
    if (ledge) {
        float ax[2][CH], ay[2][CH], aw[2][CH], ap[2][CH];
        float l1e0 = 0.f, l1e1 = 0.f;
#pragma unroll
        for (int s = 0; s < 2; ++s)
#pragma unroll
            for (int c = 0; c < CH; ++c) {
                ax[s][c] = 0.f; ay[s][c] = 0.f; aw[s][c] = 0.f; ap[s][c] = 0.f;
            }
#pragma unroll
        for (int i = 0; i < 4; ++i) {
#pragma unroll
            for (int c = 0; c < CH; ++c) {
                const float x0 = pb[c][offM[i]],      x1 = pb[c][offM[i] + 1];
                const float y0 = pb[CH + c][offM[i]], y1 = pb[CH + c][offM[i] + 1];
                const float tx = fmaf(2.f, x1, x0);                  // x1+x0+x1
                const float ty = fmaf(2.f, y1, y0);
                const float tw = fmaf(2.f, fmaf(x1, x1, y1 * y1),
                                           fmaf(x0, x0, y0 * y0));
                const float tp = fmaf(2.f, x1 * y1, x0 * y0);
                if (i < 3) { ax[0][c] += tx; ay[0][c] += ty;
                             aw[0][c] += tw; ap[0][c] += tp; }
                if (i > 0) { ax[1][c] += tx; ay[1][c] += ty;
                             aw[1][c] += tw; ap[1][c] += tp; }
                if (i == 1) l1e0 += fabsf(x0 - y0);
                if (i == 2) l1e1 += fabsf(x0 - y0);
            }
        }
        float eo0 = (0.15f / 3.f) * l1e0;
        float eo1 = (0.15f / 3.f) * l1e1;
#pragma unroll
        for (int s = 0; s < 2; ++s) {
#pragma unroll
            for (int c = 0; c < CH; ++c) {
                const float AX = ax[s][c], AY = ay[s][c];
                const float AW = aw[s][c], AP = ap[s][c];
                const float u = AX * AY;
                const float v = fmaf(AY, AY, AX * AX);
                const float n1 = fmaf(2.0f, u, K1);
                const float n2 = fmaf(18.0f, AP, fmaf(-2.0f, u, K2));
                const float d1 = v + K1;
                const float d2 = fmaf(9.0f, AW, K2) - v;
                float sv = fmaf(-0.5f, (n1 * n2) *
                                __builtin_amdgcn_rcpf(d1 * d2), 0.5f);
                sv = fminf(fmaxf(sv, 0.0f), 1.0f);
                if (s == 0) eo0 = fmaf(0.85f / 3.f, sv, eo0);
                else        eo1 = fmaf(0.85f / 3.f, sv, eo1);
            }
        }
        op0[0] = eo0;
        op1[0] = eo1;
    }
}

extern "C" void kernel_launch(void* const* d_in, const int* in_sizes, int n_in,
                              void* d_out, int out_size, void* d_ws, size_t ws_size,
                              hipStream_t stream) {
    const float* pred = (const float*)d_in[0];
    const float* gt   = (const float*)d_in[1];
    float* out = (float*)d_out;

    dim3 block(64, 4, 1);
    dim3 grid(IMG_W / 128, IMG_H / 8, 4);   // 15 x 135 x 4
    dssim_l1_kernel<<<grid, block, 0, stream>>>(pred, gt, out);
}

// Round 15
// 57.043 us; speedup vs baseline: 1.1610x; 1.1610x over previous
//
#include <hip/hip_runtime.h>

#define IMG_H 1080
#define IMG_W 1920
#define CH 3

typedef float f32x2 __attribute__((ext_vector_type(2)));

#if __has_builtin(__builtin_elementwise_fma)
#define FMA2(a, b, c) __builtin_elementwise_fma((a), (b), (c))
#else
#define FMA2(a, b, c) ((a) * (b) + (c))
#endif

// DPP wave shifts: single VALU op, no DS pipe, no lgkmcnt.
// wave_shr:1 (0x138): lane i <- lane i-1  (== shfl_up  by 1); lane 0  keeps old
// wave_shl:1 (0x130): lane i <- lane i+1  (== shfl_down by 1); lane 63 keeps old
__device__ __forceinline__ float dpp_up1(float x) {
    int i = __float_as_int(x);
    return __int_as_float(__builtin_amdgcn_update_dpp(i, i, 0x138, 0xF, 0xF, false));
}
__device__ __forceinline__ float dpp_dn1(float x) {
    int i = __float_as_int(x);
    return __int_as_float(__builtin_amdgcn_update_dpp(i, i, 0x130, 0xF, 0xF, false));
}

__global__ __launch_bounds__(256)
void dssim_l1_kernel(const float* __restrict__ pred,
                     const float* __restrict__ gt,
                     float* __restrict__ out) {
    constexpr float K1 = 81.0f * 0.0001f;        // 81*C1
    constexpr float K2 = 81.0f * 0.0009f;        // 81*C2

    const f32x2 k1_ = K1, k2_ = K2;
    const f32x2 two_ = 2.0f, m2_ = -2.0f, e18_ = 18.0f, n9_ = 9.0f;
    const f32x2 mh_ = -0.5f, h_ = 0.5f, zero_ = 0.0f, one_ = 1.0f;
    const f32x2 a3_ = 0.85f / 3.0f, b3_ = 0.15f / 3.0f;

    const int lane = threadIdx.x;                               // 0..63
    const int r0   = (blockIdx.y * 4 + threadIdx.y) * 2;        // even output row
    const int b    = blockIdx.z;
    const int c0   = blockIdx.x * 128 + 2 * lane;               // 2 output cols

    // input rows r0-1 .. r0+2 with reflection
    const int rws[4] = { (r0 == 0) ? 1 : r0 - 1,
                         r0, r0 + 1,
                         (r0 + 2 == IMG_H) ? IMG_H - 2 : r0 + 2 };

    const bool l0 = (lane == 0), l63 = (lane == 63);
    const bool limg = l0  && (blockIdx.x == 0);    // image left edge lane
    const bool rimg = l63 && (blockIdx.x == 14);   // image right edge lane
    const int  hcol = l0 ? max(c0 - 1, 0) : min(c0 + 2, IMG_W - 1);
    const bool is_edge = l0 || l63;

    const size_t img = (size_t)IMG_H * IMG_W;
    const float* __restrict__ pb[2 * CH] = {
        pred + (size_t)b * CH * img,
        pred + (size_t)b * CH * img + img,
        pred + (size_t)b * CH * img + 2 * img,
        gt   + (size_t)b * CH * img,
        gt   + (size_t)b * CH * img + img,
        gt   + (size_t)b * CH * img + 2 * img };

    // shared 32-bit voffsets (one per input row, reused across all 6 planes)
    unsigned off[4];
#pragma unroll
    for (int i = 0; i < 4; ++i) off[i] = (unsigned)rws[i] * IMG_W + (unsigned)c0;

    // ---- halo loads first (R11 lesson: last-issued halo forces full drain) ----
    float hx[4][CH], hy[4][CH];
    if (is_edge) {
        const unsigned hbase = (unsigned)hcol - (unsigned)c0;  // constant delta
#pragma unroll
        for (int i = 0; i < 4; ++i) {
            const unsigned ho = off[i] + hbase;
#pragma unroll
            for (int c = 0; c < CH; ++c) {
                hx[i][c] = pb[c][ho];
                hy[i][c] = pb[CH + c][ho];
            }
        }
    }

    // ---- main 24 packed-pair loads ----
    f32x2 qx[4][CH], qy[4][CH];
#pragma unroll
    for (int i = 0; i < 4; ++i) {
#pragma unroll
        for (int c = 0; c < CH; ++c) {
            qx[i][c] = *reinterpret_cast<const f32x2*>(pb[c]      + off[i]);
            qy[i][c] = *reinterpret_cast<const f32x2*>(pb[CH + c] + off[i]);
        }
    }

    // window accumulators, packed over the 2 output columns
    f32x2 Ax[CH], Ay[CH], Aw[CH], Ap[CH];   // rows -1,0,1 -> out r0
    f32x2 Bx[CH], By[CH], Bw[CH], Bp[CH];   // rows 0,1,2  -> out r0+1

#define CONSUME(I, DOA, FIRSTA, DOB, FIRSTB)                                \
    _Pragma("unroll")                                                       \
    for (int c = 0; c < CH; ++c) {                                          \
        const f32x2 qxv = qx[I][c], qyv = qy[I][c];                         \
        float xm = dpp_up1(qxv.y), ym = dpp_up1(qyv.y);                     \
        float xp = dpp_dn1(qxv.x), yp = dpp_dn1(qyv.x);                     \
        if (l0)   { xm = hx[I][c]; ym = hy[I][c]; }                         \
        if (l63)  { xp = hx[I][c]; yp = hy[I][c]; }                         \
        if (limg) { xm = qxv.y; ym = qyv.y; }      /* reflect(-1)=1 */      \
        if (rimg) { xp = qxv.x; yp = qyv.x; }      /* reflect(1920)=1918 */ \
        const f32x2 X0 = { xm, qxv.x }, X2 = { qxv.y, xp };                 \
        const f32x2 Y0 = { ym, qyv.x }, Y2 = { qyv.y, yp };                 \
        const f32x2 WX = X0 + qxv + X2;                                     \
        const f32x2 WY = Y0 + qyv + Y2;                                     \
        const f32x2 WP = FMA2(X2, Y2, FMA2(qxv, qyv, X0 * Y0));             \
        const f32x2 WW = FMA2(X2, X2, FMA2(Y2, Y2, FMA2(qxv, qxv,           \
                         FMA2(qyv, qyv, FMA2(X0, X0, Y0 * Y0)))));          \
        if (DOA) {                                                          \
            if (FIRSTA) { Ax[c] = WX; Ay[c] = WY; Aw[c] = WW; Ap[c] = WP; } \
            else        { Ax[c] += WX; Ay[c] += WY;                         \
                          Aw[c] += WW; Ap[c] += WP; }                       \
        }                                                                   \
        if (DOB) {                                                          \
            if (FIRSTB) { Bx[c] = WX; By[c] = WY; Bw[c] = WW; Bp[c] = WP; } \
            else        { Bx[c] += WX; By[c] += WY;                         \
                          Bw[c] += WW; Bp[c] += WP; }                       \
        }                                                                   \
    }

    CONSUME(0, true, true,  false, false)   // row r0-1 -> A
    CONSUME(1, true, false, true,  true)    // row r0   -> A, B
    CONSUME(2, true, false, true,  false)   // row r0+1 -> A, B
    CONSUME(3, false, false, true, false)   // row r0+2 -> B
#undef CONSUME

    // L1 terms from raw center rows (row idx 1 -> out r0, idx 2 -> out r0+1)
    f32x2 l1r0 = zero_, l1r1 = zero_;
#pragma unroll
    for (int c = 0; c < CH; ++c) {
#if __has_builtin(__builtin_elementwise_abs)
        l1r0 += __builtin_elementwise_abs(qx[1][c] - qy[1][c]);
        l1r1 += __builtin_elementwise_abs(qx[2][c] - qy[2][c]);
#else
        f32x2 d0 = qx[1][c] - qy[1][c], d1 = qx[2][c] - qy[2][c];
        d0.x = fabsf(d0.x); d0.y = fabsf(d0.y);
        d1.x = fabsf(d1.x); d1.y = fabsf(d1.y);
        l1r0 += d0; l1r1 += d1;
#endif
    }

    // ---- packed SSIM epilogue (moments scaled by 81; cancels in n/d) ----
#define SSIM2(AX, AY, AW, AP, ACC)                                          \
    {                                                                       \
        const f32x2 u  = (AX) * (AY);                                       \
        const f32x2 v  = FMA2((AY), (AY), (AX) * (AX));                     \
        const f32x2 n1 = FMA2(two_, u, k1_);                                \
        const f32x2 n2 = FMA2(e18_, (AP), FMA2(m2_, u, k2_));               \
        const f32x2 d1 = v + k1_;                                           \
        const f32x2 d2 = FMA2(n9_, (AW), k2_) - v;                          \
        const f32x2 nd = n1 * n2, dd = d1 * d2;                             \
        f32x2 rc;                                                           \
        rc.x = __builtin_amdgcn_rcpf(dd.x);                                 \
        rc.y = __builtin_amdgcn_rcpf(dd.y);                                 \
        f32x2 s = FMA2(mh_, nd * rc, h_);                                   \
        s = __builtin_elementwise_min(                                      \
                __builtin_elementwise_max(s, zero_), one_);                 \
        ACC = FMA2(a3_, s, ACC);                                            \
    }

    f32x2 o0 = b3_ * l1r0;
    f32x2 o1 = b3_ * l1r1;
#pragma unroll
    for (int c = 0; c < CH; ++c) {
        SSIM2(Ax[c], Ay[c], Aw[c], Ap[c], o0)
        SSIM2(Bx[c], By[c], Bw[c], Bp[c], o1)
    }
#undef SSIM2

    float* op = out + ((size_t)b * IMG_H + r0) * IMG_W + c0;
    *reinterpret_cast<f32x2*>(op) = o0;
    *reinterpret_cast<f32x2*>(op + IMG_W) = o1;
}

extern "C" void kernel_launch(void* const* d_in, const int* in_sizes, int n_in,
                              void* d_out, int out_size, void* d_ws, size_t ws_size,
                              hipStream_t stream) {
    const float* pred = (const float*)d_in[0];
    const float* gt   = (const float*)d_in[1];
    float* out = (float*)d_out;

    dim3 block(64, 4, 1);
    dim3 grid(IMG_W / 128, IMG_H / 8, 4);   // 15 x 135 x 4
    dssim_l1_kernel<<<grid, block, 0, stream>>>(pred, gt, out);
}